// Round 16
// baseline (885.167 us; speedup 1.0000x reference)
//
#include <hip/hip_runtime.h>
#include <hip/hip_fp16.h>

typedef int v4i __attribute__((ext_vector_type(4)));

#define AS1C(p) ((const __attribute__((address_space(1))) void*)(p))
#define AS3(p)  ((__attribute__((address_space(3))) void*)(p))

// ---------------------------------------------------------------------------
// pack1: int32->int8 for x and w1 + zero amax. Runs before fc1 (~237 MB,
// at HBM floor ~40us).
// ---------------------------------------------------------------------------
__global__ void pack1(const int* __restrict__ a, const int* __restrict__ b,
                      signed char* __restrict__ pa, signed char* __restrict__ pb,
                      unsigned int* __restrict__ amax,
                      long long na, long long nb, int T) {
  const long long gid = blockIdx.x * (long long)blockDim.x + threadIdx.x;
  if (gid < T) amax[gid] = 0u;
  const long long n4a = na >> 2, n4b = nb >> 2;
  const long long tot = n4a + n4b;
  const long long stride = (long long)gridDim.x * blockDim.x;
  for (long long u = gid; u < tot; u += stride) {
    const int* src; signed char* dst; long long loc;
    if (u < n4a) { src = a; dst = pa; loc = u; }
    else         { src = b; dst = pb; loc = u - n4a; }
    const int4 v = *(const int4*)(src + (loc << 2));
    const unsigned out = (unsigned)(v.x & 0xff) | ((unsigned)(v.y & 0xff) << 8) |
                         ((unsigned)(v.z & 0xff) << 16) | ((unsigned)(v.w & 0xff) << 24);
    *(unsigned*)(dst + (loc << 2)) = out;
  }
}

// ---------------------------------------------------------------------------
// fc1 fused (r15-exact): blocks [0,62) pack w2; blocks [62,512) run the
// 256x256 / 16-wave / 64KB-dbuf GEMM. 512 = exact 2-blocks/CU co-residency.
// ---------------------------------------------------------------------------
__launch_bounds__(1024, 4)
__global__ void fc1_fused(const signed char* __restrict__ A, const signed char* __restrict__ Bw,
                          int M, int N, int K,
                          const float* __restrict__ scale_tok, const float* __restrict__ wsc,
                          const float* __restrict__ bias,
                          __half* __restrict__ gout, unsigned int* __restrict__ amax,
                          const int* __restrict__ w2src, signed char* __restrict__ w2dst,
                          long long n4w2, int npack, int gy) {
  __shared__ __align__(16) char smem[2][32768];   // per buf: A 16KB | B 16KB
  const int bid = blockIdx.x;

  if (bid < npack) {
    const long long stride = (long long)npack * 1024;
    for (long long u = (long long)bid * 1024 + threadIdx.x; u < n4w2; u += stride) {
      const int4 v = *(const int4*)(w2src + (u << 2));
      const unsigned out = (unsigned)(v.x & 0xff) | ((unsigned)(v.y & 0xff) << 8) |
                           ((unsigned)(v.z & 0xff) << 16) | ((unsigned)(v.w & 0xff) << 24);
      *(unsigned*)(w2dst + (u << 2)) = out;
    }
    return;
  }

  const int tid = threadIdx.x;
  const int lane = tid & 63, wave = tid >> 6;
  const int wavem = wave >> 2, waven = wave & 3;
  const int lh = lane & 15, sseg = lane >> 4;

  int lid;
  {
    const int o = bid - npack;
    const int nwg = gridDim.x - npack;
    const int q = nwg >> 3, r = nwg & 7;
    const int x = o & 7, p = o >> 3;
    lid = (x < r ? x * (q + 1) : r * (q + 1) + (x - r) * q) + p;
  }
  const long long t0 = (long long)(lid % gy) * 256;
  const long long n0 = (long long)(lid / gy) * 256;
  const int nk = K >> 6;
  const long long Mm1 = M - 1, Nm1 = N - 1;

  const int lr4 = lane >> 2, slot = lane & 3;
  const int rloc = wave * 16 + lr4;
  const int gslot = (slot ^ ((rloc >> 1) & 3)) << 4;
  const signed char* sp0;
  const signed char* sp1;
  {
    long long gr = t0 + rloc; if (gr > Mm1) gr = Mm1;
    sp0 = A + gr * (long long)K + gslot;
    long long gn = n0 + rloc; if (gn > Nm1) gn = Nm1;
    sp1 = Bw + gn * (long long)K + gslot;
  }
  const int d0 = wave * 1024, d1 = 16384 + wave * 1024;

#define STAGE(bi) do { \
    __builtin_amdgcn_global_load_lds(AS1C(sp0), AS3(&smem[bi][d0]), 16, 0, 0); sp0 += 64; \
    __builtin_amdgcn_global_load_lds(AS1C(sp1), AS3(&smem[bi][d1]), 16, 0, 0); sp1 += 64; \
  } while (0)

  const int xs = ((sseg ^ ((lh >> 1) & 3)) << 4);
  const int offA = wavem * 4096 + lh * 64 + xs;
  const int offB = 16384 + waven * 4096 + lh * 64 + xs;

  v4i acc[4][4] = {};

  STAGE(0);
  __syncthreads();

  int cur = 0;
  for (int kt = 0; kt < nk; ++kt) {
    if (kt + 1 < nk) STAGE(cur ^ 1);
    const char* base = smem[cur];
    v4i af[4], bf[2];
#pragma unroll
    for (int mi = 0; mi < 4; ++mi) af[mi] = *(const v4i*)(base + offA + mi * 1024);
    bf[0] = *(const v4i*)(base + offB);
    bf[1] = *(const v4i*)(base + offB + 1024);
#pragma unroll
    for (int mi = 0; mi < 4; ++mi) {
      acc[mi][0] = __builtin_amdgcn_mfma_i32_16x16x64_i8(af[mi], bf[0], acc[mi][0], 0, 0, 0);
      acc[mi][1] = __builtin_amdgcn_mfma_i32_16x16x64_i8(af[mi], bf[1], acc[mi][1], 0, 0, 0);
    }
    bf[0] = *(const v4i*)(base + offB + 2048);
    bf[1] = *(const v4i*)(base + offB + 3072);
#pragma unroll
    for (int mi = 0; mi < 4; ++mi) {
      acc[mi][2] = __builtin_amdgcn_mfma_i32_16x16x64_i8(af[mi], bf[0], acc[mi][2], 0, 0, 0);
      acc[mi][3] = __builtin_amdgcn_mfma_i32_16x16x64_i8(af[mi], bf[1], acc[mi][3], 0, 0, 0);
    }
    __syncthreads();
    cur ^= 1;
  }
#undef STAGE

  long long cidx[4]; float w4[4], bi4[4]; bool cok[4];
#pragma unroll
  for (int ni = 0; ni < 4; ++ni) {
    cidx[ni] = n0 + waven * 64 + ni * 16 + lh;
    cok[ni] = cidx[ni] < N;
    w4[ni] = cok[ni] ? wsc[cidx[ni]] : 0.f;
    bi4[ni] = cok[ni] ? bias[cidx[ni]] : 0.f;
  }
#pragma unroll
  for (int mi = 0; mi < 4; ++mi) {
#pragma unroll
    for (int j = 0; j < 4; ++j) {
      const long long t = t0 + wavem * 64 + mi * 16 + (lane >> 4) * 4 + j;
      const bool valid = t < M;
      const float st = valid ? scale_tok[t] : 0.f;
      float rowmax = 0.f;
#pragma unroll
      for (int ni = 0; ni < 4; ++ni) {
        float v = (float)acc[mi][ni][j] * st * w4[ni] + bi4[ni];
        v = __half2float(__float2half(v));  // fc1 rounds to fp16 (reference)
        const float gl = 0.5f * v * (1.f + erff(v * 0.70710678118654752f));
        rowmax = fmaxf(rowmax, fabsf(gl));
        if (valid && cok[ni]) gout[t * (long long)N + cidx[ni]] = __float2half(gl);
      }
#pragma unroll
      for (int m = 1; m < 16; m <<= 1) rowmax = fmaxf(rowmax, __shfl_xor(rowmax, m));
      if (valid && lh == 0) atomicMax(&amax[t], __float_as_uint(rowmax));
    }
  }
}

// ---------------------------------------------------------------------------
// fc2: 128x256 tile (intensity 85 ops/staged-B vs 64 for 128^2), 8 waves
// (512 thr, 2M x 4N, wave tile 64x64 — fc1's verified fragment math),
// 48KB dbuf -> 3 blocks/CU (24 waves/CU). 221 blocks. Staging 3 chunks/thr.
// ---------------------------------------------------------------------------
__launch_bounds__(512, 6)
__global__ void gemm_fc2(const signed char* __restrict__ A, const signed char* __restrict__ Bw,
                         int M, int N, int K,
                         const float* __restrict__ wsc, const float* __restrict__ bias,
                         unsigned int* __restrict__ amax, float* __restrict__ fout) {
  __shared__ __align__(16) char smem[2][24576];   // per buf: A 8KB | B 16KB
  const int tid = threadIdx.x;
  const int lane = tid & 63, wave = tid >> 6;
  const int wavem = wave >> 2, waven = wave & 3;   // 2M x 4N
  const int lh = lane & 15, sseg = lane >> 4;

  const int gy = gridDim.y;
  int lid;
  {
    const int o = blockIdx.y * gridDim.x + blockIdx.x;
    const int nwg = gridDim.x * gy;
    const int q = nwg >> 3, r = nwg & 7;
    const int x = o & 7, p = o >> 3;
    lid = (x < r ? x * (q + 1) : r * (q + 1) + (x - r) * q) + p;
  }
  const long long t0 = (long long)(lid % gy) * 128;
  const long long n0 = (long long)(lid / gy) * 256;
  const int nk = K >> 6;
  const long long Mm1 = M - 1, Nm1 = N - 1;

  // ---- staging: 3 chunks/wave (24 chunks: A 8 + B 16), 16B/lane
  const signed char* sp[3];
  int dst[3];
#pragma unroll
  for (int i = 0; i < 3; ++i) {
    const int c = wave * 3 + i;
    const bool isA = c < 8;
    const int lr = (isA ? c : c - 8) * 16 + (lane >> 2);
    const int gslot = (((lane & 3) ^ ((lr >> 1) & 3)) << 4);
    long long gr = isA ? (t0 + lr) : (n0 + lr);
    const long long rmax = isA ? Mm1 : Nm1;
    if (gr > rmax) gr = rmax;
    sp[i] = (isA ? A : Bw) + gr * (long long)K + gslot;
    dst[i] = c * 1024;                  // A 0..8K, B 8K..24K
  }

#define STAGE(bi) do { \
    _Pragma("unroll") \
    for (int i = 0; i < 3; ++i) { \
      __builtin_amdgcn_global_load_lds(AS1C(sp[i]), AS3(&smem[bi][dst[i]]), 16, 0, 0); \
      sp[i] += 64; \
    } \
  } while (0)

  const int xs = ((sseg ^ ((lh >> 1) & 3)) << 4);
  const int offA = wavem * 4096 + lh * 64 + xs;          // + mi*1024, mi<4
  const int offB = 8192 + waven * 4096 + lh * 64 + xs;   // + ni*1024, ni<4

  v4i acc[4][4] = {};

  STAGE(0);
  __syncthreads();

  int cur = 0;
  for (int kt = 0; kt < nk; ++kt) {
    if (kt + 1 < nk) STAGE(cur ^ 1);
    const char* base = smem[cur];
    v4i af[4], bf[2];
#pragma unroll
    for (int mi = 0; mi < 4; ++mi) af[mi] = *(const v4i*)(base + offA + mi * 1024);
    bf[0] = *(const v4i*)(base + offB);
    bf[1] = *(const v4i*)(base + offB + 1024);
#pragma unroll
    for (int mi = 0; mi < 4; ++mi) {
      acc[mi][0] = __builtin_amdgcn_mfma_i32_16x16x64_i8(af[mi], bf[0], acc[mi][0], 0, 0, 0);
      acc[mi][1] = __builtin_amdgcn_mfma_i32_16x16x64_i8(af[mi], bf[1], acc[mi][1], 0, 0, 0);
    }
    bf[0] = *(const v4i*)(base + offB + 2048);
    bf[1] = *(const v4i*)(base + offB + 3072);
#pragma unroll
    for (int mi = 0; mi < 4; ++mi) {
      acc[mi][2] = __builtin_amdgcn_mfma_i32_16x16x64_i8(af[mi], bf[0], acc[mi][2], 0, 0, 0);
      acc[mi][3] = __builtin_amdgcn_mfma_i32_16x16x64_i8(af[mi], bf[1], acc[mi][3], 0, 0, 0);
    }
    __syncthreads();
    cur ^= 1;
  }
#undef STAGE

  // ---- fc2 epilogue
  long long cidx[4]; float w4[4], bi4[4]; bool cok[4];
#pragma unroll
  for (int ni = 0; ni < 4; ++ni) {
    cidx[ni] = n0 + waven * 64 + ni * 16 + lh;
    cok[ni] = cidx[ni] < N;
    w4[ni] = cok[ni] ? wsc[cidx[ni]] : 0.f;
    bi4[ni] = cok[ni] ? bias[cidx[ni]] : 0.f;
  }
#pragma unroll
  for (int mi = 0; mi < 4; ++mi) {
#pragma unroll
    for (int j = 0; j < 4; ++j) {
      const long long t = t0 + wavem * 64 + mi * 16 + (lane >> 4) * 4 + j;
      if (t < M) {
        const float am = __uint_as_float(amax[t]);
        const float st = __half2float(__float2half(am * (1.f / 127.f)));
#pragma unroll
        for (int ni = 0; ni < 4; ++ni) {
          const float v = (float)acc[mi][ni][j] * st * w4[ni] + bi4[ni];
          if (cok[ni]) fout[t * (long long)N + cidx[ni]] = __half2float(__float2half(v));
        }
      }
    }
  }
}

// ---------------------------------------------------------------------------
// per-token dynamic int8 quantization of the GELU output
// ---------------------------------------------------------------------------
__global__ void gelu_quant(const __half* __restrict__ g, const unsigned int* __restrict__ amax,
                           signed char* __restrict__ q, long long total, int I) {
  const long long nchunk = total >> 3;
  const long long stride = (long long)gridDim.x * blockDim.x;
  for (long long c = blockIdx.x * (long long)blockDim.x + threadIdx.x; c < nchunk; c += stride) {
    const long long base = c << 3;  // 8 elems, never crosses a row (I % 8 == 0)
    const int t = (int)(base / I);
    const float am = __uint_as_float(amax[t]);
    const float s = fmaxf(__half2float(__float2half(am * (1.f / 127.f))), 1e-8f);
    const float inv = 1.f / s;
    const int4 raw = *(const int4*)(g + base);
    const __half2* h2 = (const __half2*)&raw;
    union { signed char b[8]; int2 v; } u;
#pragma unroll
    for (int k = 0; k < 4; ++k) {
      const float2 f = __half22float2(h2[k]);
      const float q0 = fminf(fmaxf(rintf(f.x * inv), -128.f), 127.f);
      const float q1 = fminf(fmaxf(rintf(f.y * inv), -128.f), 127.f);
      u.b[k * 2]     = (signed char)(int)q0;
      u.b[k * 2 + 1] = (signed char)(int)q1;
    }
    *(int2*)(q + base) = u.v;
  }
}

extern "C" void kernel_launch(void* const* d_in, const int* in_sizes, int n_in,
                              void* d_out, int out_size, void* d_ws, size_t ws_size,
                              hipStream_t stream) {
  const int* hs = (const int*)d_in[0];
  const float* scale_in = (const float*)d_in[1];   // fp16 in reference -> f32 buffer
  const int* w1 = (const int*)d_in[2];
  const float* w1s = (const float*)d_in[3];
  const float* b1 = (const float*)d_in[4];
  const int* w2 = (const int*)d_in[5];
  const float* w2s = (const float*)d_in[6];
  const float* b2 = (const float*)d_in[7];

  const int T = in_sizes[1];        // 2050
  const int I = in_sizes[3];        // 12800
  const int H = in_sizes[6];        // 3200

  char* ws = (char*)d_ws;
  unsigned int* amax = (unsigned int*)ws;                    // T u32 (16KB pad)
  signed char* px  = (signed char*)(ws + 16384);             // T*H
  signed char* pw1 = px + (size_t)T * H;                     // I*H
  signed char* pw2 = pw1 + (size_t)I * H;                    // H*I
  __half* gbuf = (__half*)(pw2 + (size_t)H * I);             // T*I fp16
  signed char* qbuf = (signed char*)(gbuf + (size_t)T * I);  // T*I

  const long long nx = (long long)T * H, nw1 = (long long)I * H, nw2 = (long long)H * I;

  // pack x + w1 (+ amax zero) — must precede fc1
  pack1<<<2048, 256, 0, stream>>>(hs, w1, px, pw1, amax, nx, nw1, T);

  // fc1 (256x256, 16 waves) fused with w2 packing; 62 + 450 = 512 blocks
  const int NPACK = 62;
  const int gy1 = (T + 255) / 256;                 // 9
  const int gemmBlocks = (I / 256) * gy1;          // 450
  fc1_fused<<<NPACK + gemmBlocks, 1024, 0, stream>>>(
      px, pw1, T, I, H, scale_in, w1s, b1, gbuf, amax,
      w2, pw2, nw2 >> 2, NPACK, gy1);

  gelu_quant<<<2048, 256, 0, stream>>>(gbuf, amax, qbuf, (long long)T * I, I);

  // fc2: 128x256 tiles, 8 waves, grid 13 x 17 = 221 blocks
  dim3 g2((H + 255) / 256, (T + 127) / 128);
  gemm_fc2<<<g2, 512, 0, stream>>>(qbuf, pw2, T, H, I, w2s, b2, amax, (float*)d_out);
}

// Round 17
// 365.764 us; speedup vs baseline: 2.4200x; 2.4200x over previous
//
#include <hip/hip_runtime.h>
#include <hip/hip_fp16.h>

typedef int v4i __attribute__((ext_vector_type(4)));

#define AS1C(p) ((const __attribute__((address_space(1))) void*)(p))
#define AS3(p)  ((__attribute__((address_space(3))) void*)(p))

// ---------------------------------------------------------------------------
// pack1: int32->int8 for x and w1 + zero amax. Runs before fc1 (~237 MB,
// at HBM floor ~40us).
// ---------------------------------------------------------------------------
__global__ void pack1(const int* __restrict__ a, const int* __restrict__ b,
                      signed char* __restrict__ pa, signed char* __restrict__ pb,
                      unsigned int* __restrict__ amax,
                      long long na, long long nb, int T) {
  const long long gid = blockIdx.x * (long long)blockDim.x + threadIdx.x;
  if (gid < T) amax[gid] = 0u;
  const long long n4a = na >> 2, n4b = nb >> 2;
  const long long tot = n4a + n4b;
  const long long stride = (long long)gridDim.x * blockDim.x;
  for (long long u = gid; u < tot; u += stride) {
    const int* src; signed char* dst; long long loc;
    if (u < n4a) { src = a; dst = pa; loc = u; }
    else         { src = b; dst = pb; loc = u - n4a; }
    const int4 v = *(const int4*)(src + (loc << 2));
    const unsigned out = (unsigned)(v.x & 0xff) | ((unsigned)(v.y & 0xff) << 8) |
                         ((unsigned)(v.z & 0xff) << 16) | ((unsigned)(v.w & 0xff) << 24);
    *(unsigned*)(dst + (loc << 2)) = out;
  }
}

// ---------------------------------------------------------------------------
// fc1 fused (r15-exact): blocks [0,62) pack w2; blocks [62,512) run the
// 256x256 / 16-wave / 64KB-dbuf GEMM. 512 = exact 2-blocks/CU co-residency.
// ---------------------------------------------------------------------------
__launch_bounds__(1024, 4)
__global__ void fc1_fused(const signed char* __restrict__ A, const signed char* __restrict__ Bw,
                          int M, int N, int K,
                          const float* __restrict__ scale_tok, const float* __restrict__ wsc,
                          const float* __restrict__ bias,
                          __half* __restrict__ gout, unsigned int* __restrict__ amax,
                          const int* __restrict__ w2src, signed char* __restrict__ w2dst,
                          long long n4w2, int npack, int gy) {
  __shared__ __align__(16) char smem[2][32768];   // per buf: A 16KB | B 16KB
  const int bid = blockIdx.x;

  if (bid < npack) {
    const long long stride = (long long)npack * 1024;
    for (long long u = (long long)bid * 1024 + threadIdx.x; u < n4w2; u += stride) {
      const int4 v = *(const int4*)(w2src + (u << 2));
      const unsigned out = (unsigned)(v.x & 0xff) | ((unsigned)(v.y & 0xff) << 8) |
                           ((unsigned)(v.z & 0xff) << 16) | ((unsigned)(v.w & 0xff) << 24);
      *(unsigned*)(w2dst + (u << 2)) = out;
    }
    return;
  }

  const int tid = threadIdx.x;
  const int lane = tid & 63, wave = tid >> 6;
  const int wavem = wave >> 2, waven = wave & 3;
  const int lh = lane & 15, sseg = lane >> 4;

  int lid;
  {
    const int o = bid - npack;
    const int nwg = gridDim.x - npack;
    const int q = nwg >> 3, r = nwg & 7;
    const int x = o & 7, p = o >> 3;
    lid = (x < r ? x * (q + 1) : r * (q + 1) + (x - r) * q) + p;
  }
  const long long t0 = (long long)(lid % gy) * 256;
  const long long n0 = (long long)(lid / gy) * 256;
  const int nk = K >> 6;
  const long long Mm1 = M - 1, Nm1 = N - 1;

  const int lr4 = lane >> 2, slot = lane & 3;
  const int rloc = wave * 16 + lr4;
  const int gslot = (slot ^ ((rloc >> 1) & 3)) << 4;
  const signed char* sp0;
  const signed char* sp1;
  {
    long long gr = t0 + rloc; if (gr > Mm1) gr = Mm1;
    sp0 = A + gr * (long long)K + gslot;
    long long gn = n0 + rloc; if (gn > Nm1) gn = Nm1;
    sp1 = Bw + gn * (long long)K + gslot;
  }
  const int d0 = wave * 1024, d1 = 16384 + wave * 1024;

#define STAGE(bi) do { \
    __builtin_amdgcn_global_load_lds(AS1C(sp0), AS3(&smem[bi][d0]), 16, 0, 0); sp0 += 64; \
    __builtin_amdgcn_global_load_lds(AS1C(sp1), AS3(&smem[bi][d1]), 16, 0, 0); sp1 += 64; \
  } while (0)

  const int xs = ((sseg ^ ((lh >> 1) & 3)) << 4);
  const int offA = wavem * 4096 + lh * 64 + xs;
  const int offB = 16384 + waven * 4096 + lh * 64 + xs;

  v4i acc[4][4] = {};

  STAGE(0);
  __syncthreads();

  int cur = 0;
  for (int kt = 0; kt < nk; ++kt) {
    if (kt + 1 < nk) STAGE(cur ^ 1);
    const char* base = smem[cur];
    v4i af[4], bf[2];
#pragma unroll
    for (int mi = 0; mi < 4; ++mi) af[mi] = *(const v4i*)(base + offA + mi * 1024);
    bf[0] = *(const v4i*)(base + offB);
    bf[1] = *(const v4i*)(base + offB + 1024);
#pragma unroll
    for (int mi = 0; mi < 4; ++mi) {
      acc[mi][0] = __builtin_amdgcn_mfma_i32_16x16x64_i8(af[mi], bf[0], acc[mi][0], 0, 0, 0);
      acc[mi][1] = __builtin_amdgcn_mfma_i32_16x16x64_i8(af[mi], bf[1], acc[mi][1], 0, 0, 0);
    }
    bf[0] = *(const v4i*)(base + offB + 2048);
    bf[1] = *(const v4i*)(base + offB + 3072);
#pragma unroll
    for (int mi = 0; mi < 4; ++mi) {
      acc[mi][2] = __builtin_amdgcn_mfma_i32_16x16x64_i8(af[mi], bf[0], acc[mi][2], 0, 0, 0);
      acc[mi][3] = __builtin_amdgcn_mfma_i32_16x16x64_i8(af[mi], bf[1], acc[mi][3], 0, 0, 0);
    }
    __syncthreads();
    cur ^= 1;
  }
#undef STAGE

  long long cidx[4]; float w4[4], bi4[4]; bool cok[4];
#pragma unroll
  for (int ni = 0; ni < 4; ++ni) {
    cidx[ni] = n0 + waven * 64 + ni * 16 + lh;
    cok[ni] = cidx[ni] < N;
    w4[ni] = cok[ni] ? wsc[cidx[ni]] : 0.f;
    bi4[ni] = cok[ni] ? bias[cidx[ni]] : 0.f;
  }
#pragma unroll
  for (int mi = 0; mi < 4; ++mi) {
#pragma unroll
    for (int j = 0; j < 4; ++j) {
      const long long t = t0 + wavem * 64 + mi * 16 + (lane >> 4) * 4 + j;
      const bool valid = t < M;
      const float st = valid ? scale_tok[t] : 0.f;
      float rowmax = 0.f;
#pragma unroll
      for (int ni = 0; ni < 4; ++ni) {
        float v = (float)acc[mi][ni][j] * st * w4[ni] + bi4[ni];
        v = __half2float(__float2half(v));  // fc1 rounds to fp16 (reference)
        const float gl = 0.5f * v * (1.f + erff(v * 0.70710678118654752f));
        rowmax = fmaxf(rowmax, fabsf(gl));
        if (valid && cok[ni]) gout[t * (long long)N + cidx[ni]] = __float2half(gl);
      }
#pragma unroll
      for (int m = 1; m < 16; m <<= 1) rowmax = fmaxf(rowmax, __shfl_xor(rowmax, m));
      if (valid && lh == 0) atomicMax(&amax[t], __float_as_uint(rowmax));
    }
  }
}

// ---------------------------------------------------------------------------
// fc2: 128x256 tile (intensity 85 ops/staged-B), 8 waves (512 thr, 2M x 4N,
// wave tile 64x64), 48KB dbuf. launch_bounds(512,4): VGPR cap 128 fits the
// ~110-reg live set (r16's (512,6) capped at ~84 -> acc spilled to scratch,
// 758MB scratch writes, 703us — the regression was the spill, not the tile).
// ---------------------------------------------------------------------------
__launch_bounds__(512, 4)
__global__ void gemm_fc2(const signed char* __restrict__ A, const signed char* __restrict__ Bw,
                         int M, int N, int K,
                         const float* __restrict__ wsc, const float* __restrict__ bias,
                         unsigned int* __restrict__ amax, float* __restrict__ fout) {
  __shared__ __align__(16) char smem[2][24576];   // per buf: A 8KB | B 16KB
  const int tid = threadIdx.x;
  const int lane = tid & 63, wave = tid >> 6;
  const int wavem = wave >> 2, waven = wave & 3;   // 2M x 4N
  const int lh = lane & 15, sseg = lane >> 4;

  const int gy = gridDim.y;
  int lid;
  {
    const int o = blockIdx.y * gridDim.x + blockIdx.x;
    const int nwg = gridDim.x * gy;
    const int q = nwg >> 3, r = nwg & 7;
    const int x = o & 7, p = o >> 3;
    lid = (x < r ? x * (q + 1) : r * (q + 1) + (x - r) * q) + p;
  }
  const long long t0 = (long long)(lid % gy) * 128;
  const long long n0 = (long long)(lid / gy) * 256;
  const int nk = K >> 6;
  const long long Mm1 = M - 1, Nm1 = N - 1;

  // ---- staging: 3 chunks/wave (24 chunks: A 8 + B 16), 16B/lane
  const signed char* sp[3];
  int dst[3];
#pragma unroll
  for (int i = 0; i < 3; ++i) {
    const int c = wave * 3 + i;
    const bool isA = c < 8;
    const int lr = (isA ? c : c - 8) * 16 + (lane >> 2);
    const int gslot = (((lane & 3) ^ ((lr >> 1) & 3)) << 4);
    long long gr = isA ? (t0 + lr) : (n0 + lr);
    const long long rmax = isA ? Mm1 : Nm1;
    if (gr > rmax) gr = rmax;
    sp[i] = (isA ? A : Bw) + gr * (long long)K + gslot;
    dst[i] = c * 1024;                  // A 0..8K, B 8K..24K
  }

#define STAGE(bi) do { \
    _Pragma("unroll") \
    for (int i = 0; i < 3; ++i) { \
      __builtin_amdgcn_global_load_lds(AS1C(sp[i]), AS3(&smem[bi][dst[i]]), 16, 0, 0); \
      sp[i] += 64; \
    } \
  } while (0)

  const int xs = ((sseg ^ ((lh >> 1) & 3)) << 4);
  const int offA = wavem * 4096 + lh * 64 + xs;          // + mi*1024, mi<4
  const int offB = 8192 + waven * 4096 + lh * 64 + xs;   // + ni*1024, ni<4

  v4i acc[4][4] = {};

  STAGE(0);
  __syncthreads();

  int cur = 0;
  for (int kt = 0; kt < nk; ++kt) {
    if (kt + 1 < nk) STAGE(cur ^ 1);
    const char* base = smem[cur];
    v4i af[4], bf[2];
#pragma unroll
    for (int mi = 0; mi < 4; ++mi) af[mi] = *(const v4i*)(base + offA + mi * 1024);
    bf[0] = *(const v4i*)(base + offB);
    bf[1] = *(const v4i*)(base + offB + 1024);
#pragma unroll
    for (int mi = 0; mi < 4; ++mi) {
      acc[mi][0] = __builtin_amdgcn_mfma_i32_16x16x64_i8(af[mi], bf[0], acc[mi][0], 0, 0, 0);
      acc[mi][1] = __builtin_amdgcn_mfma_i32_16x16x64_i8(af[mi], bf[1], acc[mi][1], 0, 0, 0);
    }
    bf[0] = *(const v4i*)(base + offB + 2048);
    bf[1] = *(const v4i*)(base + offB + 3072);
#pragma unroll
    for (int mi = 0; mi < 4; ++mi) {
      acc[mi][2] = __builtin_amdgcn_mfma_i32_16x16x64_i8(af[mi], bf[0], acc[mi][2], 0, 0, 0);
      acc[mi][3] = __builtin_amdgcn_mfma_i32_16x16x64_i8(af[mi], bf[1], acc[mi][3], 0, 0, 0);
    }
    __syncthreads();
    cur ^= 1;
  }
#undef STAGE

  // ---- fc2 epilogue
  long long cidx[4]; float w4[4], bi4[4]; bool cok[4];
#pragma unroll
  for (int ni = 0; ni < 4; ++ni) {
    cidx[ni] = n0 + waven * 64 + ni * 16 + lh;
    cok[ni] = cidx[ni] < N;
    w4[ni] = cok[ni] ? wsc[cidx[ni]] : 0.f;
    bi4[ni] = cok[ni] ? bias[cidx[ni]] : 0.f;
  }
#pragma unroll
  for (int mi = 0; mi < 4; ++mi) {
#pragma unroll
    for (int j = 0; j < 4; ++j) {
      const long long t = t0 + wavem * 64 + mi * 16 + (lane >> 4) * 4 + j;
      if (t < M) {
        const float am = __uint_as_float(amax[t]);
        const float st = __half2float(__float2half(am * (1.f / 127.f)));
#pragma unroll
        for (int ni = 0; ni < 4; ++ni) {
          const float v = (float)acc[mi][ni][j] * st * w4[ni] + bi4[ni];
          if (cok[ni]) fout[t * (long long)N + cidx[ni]] = __half2float(__float2half(v));
        }
      }
    }
  }
}

// ---------------------------------------------------------------------------
// per-token dynamic int8 quantization of the GELU output
// ---------------------------------------------------------------------------
__global__ void gelu_quant(const __half* __restrict__ g, const unsigned int* __restrict__ amax,
                           signed char* __restrict__ q, long long total, int I) {
  const long long nchunk = total >> 3;
  const long long stride = (long long)gridDim.x * blockDim.x;
  for (long long c = blockIdx.x * (long long)blockDim.x + threadIdx.x; c < nchunk; c += stride) {
    const long long base = c << 3;  // 8 elems, never crosses a row (I % 8 == 0)
    const int t = (int)(base / I);
    const float am = __uint_as_float(amax[t]);
    const float s = fmaxf(__half2float(__float2half(am * (1.f / 127.f))), 1e-8f);
    const float inv = 1.f / s;
    const int4 raw = *(const int4*)(g + base);
    const __half2* h2 = (const __half2*)&raw;
    union { signed char b[8]; int2 v; } u;
#pragma unroll
    for (int k = 0; k < 4; ++k) {
      const float2 f = __half22float2(h2[k]);
      const float q0 = fminf(fmaxf(rintf(f.x * inv), -128.f), 127.f);
      const float q1 = fminf(fmaxf(rintf(f.y * inv), -128.f), 127.f);
      u.b[k * 2]     = (signed char)(int)q0;
      u.b[k * 2 + 1] = (signed char)(int)q1;
    }
    *(int2*)(q + base) = u.v;
  }
}

extern "C" void kernel_launch(void* const* d_in, const int* in_sizes, int n_in,
                              void* d_out, int out_size, void* d_ws, size_t ws_size,
                              hipStream_t stream) {
  const int* hs = (const int*)d_in[0];
  const float* scale_in = (const float*)d_in[1];   // fp16 in reference -> f32 buffer
  const int* w1 = (const int*)d_in[2];
  const float* w1s = (const float*)d_in[3];
  const float* b1 = (const float*)d_in[4];
  const int* w2 = (const int*)d_in[5];
  const float* w2s = (const float*)d_in[6];
  const float* b2 = (const float*)d_in[7];

  const int T = in_sizes[1];        // 2050
  const int I = in_sizes[3];        // 12800
  const int H = in_sizes[6];        // 3200

  char* ws = (char*)d_ws;
  unsigned int* amax = (unsigned int*)ws;                    // T u32 (16KB pad)
  signed char* px  = (signed char*)(ws + 16384);             // T*H
  signed char* pw1 = px + (size_t)T * H;                     // I*H
  signed char* pw2 = pw1 + (size_t)I * H;                    // H*I
  __half* gbuf = (__half*)(pw2 + (size_t)H * I);             // T*I fp16
  signed char* qbuf = (signed char*)(gbuf + (size_t)T * I);  // T*I

  const long long nx = (long long)T * H, nw1 = (long long)I * H, nw2 = (long long)H * I;

  // pack x + w1 (+ amax zero) — must precede fc1
  pack1<<<2048, 256, 0, stream>>>(hs, w1, px, pw1, amax, nx, nw1, T);

  // fc1 (256x256, 16 waves) fused with w2 packing; 62 + 450 = 512 blocks
  const int NPACK = 62;
  const int gy1 = (T + 255) / 256;                 // 9
  const int gemmBlocks = (I / 256) * gy1;          // 450
  fc1_fused<<<NPACK + gemmBlocks, 1024, 0, stream>>>(
      px, pw1, T, I, H, scale_in, w1s, b1, gbuf, amax,
      w2, pw2, nw2 >> 2, NPACK, gy1);

  gelu_quant<<<2048, 256, 0, stream>>>(gbuf, amax, qbuf, (long long)T * I, I);

  // fc2: 128x256 tiles, 8 waves, grid 13 x 17 = 221 blocks
  dim3 g2((H + 255) / 256, (T + 127) / 128);
  gemm_fc2<<<g2, 512, 0, stream>>>(qbuf, pw2, T, H, I, w2s, b2, amax, (float*)d_out);
}

// Round 18
// 340.163 us; speedup vs baseline: 2.6022x; 1.0753x over previous
//
#include <hip/hip_runtime.h>
#include <hip/hip_fp16.h>

typedef int v4i __attribute__((ext_vector_type(4)));

#define AS1C(p) ((const __attribute__((address_space(1))) void*)(p))
#define AS3(p)  ((__attribute__((address_space(3))) void*)(p))

// ---------------------------------------------------------------------------
// pack1: int32->int8 for x and w1 + zero amax. Runs before fc1 (~237 MB).
// ---------------------------------------------------------------------------
__global__ void pack1(const int* __restrict__ a, const int* __restrict__ b,
                      signed char* __restrict__ pa, signed char* __restrict__ pb,
                      unsigned int* __restrict__ amax,
                      long long na, long long nb, int T) {
  const long long gid = blockIdx.x * (long long)blockDim.x + threadIdx.x;
  if (gid < T) amax[gid] = 0u;
  const long long n4a = na >> 2, n4b = nb >> 2;
  const long long tot = n4a + n4b;
  const long long stride = (long long)gridDim.x * blockDim.x;
  for (long long u = gid; u < tot; u += stride) {
    const int* src; signed char* dst; long long loc;
    if (u < n4a) { src = a; dst = pa; loc = u; }
    else         { src = b; dst = pb; loc = u - n4a; }
    const int4 v = *(const int4*)(src + (loc << 2));
    const unsigned out = (unsigned)(v.x & 0xff) | ((unsigned)(v.y & 0xff) << 8) |
                         ((unsigned)(v.z & 0xff) << 16) | ((unsigned)(v.w & 0xff) << 24);
    *(unsigned*)(dst + (loc << 2)) = out;
  }
}

// ---------------------------------------------------------------------------
// fc1 fused (r15-exact): blocks [0,62) pack w2; blocks [62,512) run the
// 256x256 / 16-wave / 64KB-dbuf GEMM. 512 = exact 2-blocks/CU co-residency.
// ---------------------------------------------------------------------------
__launch_bounds__(1024, 4)
__global__ void fc1_fused(const signed char* __restrict__ A, const signed char* __restrict__ Bw,
                          int M, int N, int K,
                          const float* __restrict__ scale_tok, const float* __restrict__ wsc,
                          const float* __restrict__ bias,
                          __half* __restrict__ gout, unsigned int* __restrict__ amax,
                          const int* __restrict__ w2src, signed char* __restrict__ w2dst,
                          long long n4w2, int npack, int gy) {
  __shared__ __align__(16) char smem[2][32768];   // per buf: A 16KB | B 16KB
  const int bid = blockIdx.x;

  if (bid < npack) {
    const long long stride = (long long)npack * 1024;
    for (long long u = (long long)bid * 1024 + threadIdx.x; u < n4w2; u += stride) {
      const int4 v = *(const int4*)(w2src + (u << 2));
      const unsigned out = (unsigned)(v.x & 0xff) | ((unsigned)(v.y & 0xff) << 8) |
                           ((unsigned)(v.z & 0xff) << 16) | ((unsigned)(v.w & 0xff) << 24);
      *(unsigned*)(w2dst + (u << 2)) = out;
    }
    return;
  }

  const int tid = threadIdx.x;
  const int lane = tid & 63, wave = tid >> 6;
  const int wavem = wave >> 2, waven = wave & 3;
  const int lh = lane & 15, sseg = lane >> 4;

  int lid;
  {
    const int o = bid - npack;
    const int nwg = gridDim.x - npack;
    const int q = nwg >> 3, r = nwg & 7;
    const int x = o & 7, p = o >> 3;
    lid = (x < r ? x * (q + 1) : r * (q + 1) + (x - r) * q) + p;
  }
  const long long t0 = (long long)(lid % gy) * 256;
  const long long n0 = (long long)(lid / gy) * 256;
  const int nk = K >> 6;
  const long long Mm1 = M - 1, Nm1 = N - 1;

  const int lr4 = lane >> 2, slot = lane & 3;
  const int rloc = wave * 16 + lr4;
  const int gslot = (slot ^ ((rloc >> 1) & 3)) << 4;
  const signed char* sp0;
  const signed char* sp1;
  {
    long long gr = t0 + rloc; if (gr > Mm1) gr = Mm1;
    sp0 = A + gr * (long long)K + gslot;
    long long gn = n0 + rloc; if (gn > Nm1) gn = Nm1;
    sp1 = Bw + gn * (long long)K + gslot;
  }
  const int d0 = wave * 1024, d1 = 16384 + wave * 1024;

#define STAGE(bi) do { \
    __builtin_amdgcn_global_load_lds(AS1C(sp0), AS3(&smem[bi][d0]), 16, 0, 0); sp0 += 64; \
    __builtin_amdgcn_global_load_lds(AS1C(sp1), AS3(&smem[bi][d1]), 16, 0, 0); sp1 += 64; \
  } while (0)

  const int xs = ((sseg ^ ((lh >> 1) & 3)) << 4);
  const int offA = wavem * 4096 + lh * 64 + xs;
  const int offB = 16384 + waven * 4096 + lh * 64 + xs;

  v4i acc[4][4] = {};

  STAGE(0);
  __syncthreads();

  int cur = 0;
  for (int kt = 0; kt < nk; ++kt) {
    if (kt + 1 < nk) STAGE(cur ^ 1);
    const char* base = smem[cur];
    v4i af[4], bf[2];
#pragma unroll
    for (int mi = 0; mi < 4; ++mi) af[mi] = *(const v4i*)(base + offA + mi * 1024);
    bf[0] = *(const v4i*)(base + offB);
    bf[1] = *(const v4i*)(base + offB + 1024);
#pragma unroll
    for (int mi = 0; mi < 4; ++mi) {
      acc[mi][0] = __builtin_amdgcn_mfma_i32_16x16x64_i8(af[mi], bf[0], acc[mi][0], 0, 0, 0);
      acc[mi][1] = __builtin_amdgcn_mfma_i32_16x16x64_i8(af[mi], bf[1], acc[mi][1], 0, 0, 0);
    }
    bf[0] = *(const v4i*)(base + offB + 2048);
    bf[1] = *(const v4i*)(base + offB + 3072);
#pragma unroll
    for (int mi = 0; mi < 4; ++mi) {
      acc[mi][2] = __builtin_amdgcn_mfma_i32_16x16x64_i8(af[mi], bf[0], acc[mi][2], 0, 0, 0);
      acc[mi][3] = __builtin_amdgcn_mfma_i32_16x16x64_i8(af[mi], bf[1], acc[mi][3], 0, 0, 0);
    }
    __syncthreads();
    cur ^= 1;
  }
#undef STAGE

  long long cidx[4]; float w4[4], bi4[4]; bool cok[4];
#pragma unroll
  for (int ni = 0; ni < 4; ++ni) {
    cidx[ni] = n0 + waven * 64 + ni * 16 + lh;
    cok[ni] = cidx[ni] < N;
    w4[ni] = cok[ni] ? wsc[cidx[ni]] : 0.f;
    bi4[ni] = cok[ni] ? bias[cidx[ni]] : 0.f;
  }
#pragma unroll
  for (int mi = 0; mi < 4; ++mi) {
#pragma unroll
    for (int j = 0; j < 4; ++j) {
      const long long t = t0 + wavem * 64 + mi * 16 + (lane >> 4) * 4 + j;
      const bool valid = t < M;
      const float st = valid ? scale_tok[t] : 0.f;
      float rowmax = 0.f;
#pragma unroll
      for (int ni = 0; ni < 4; ++ni) {
        float v = (float)acc[mi][ni][j] * st * w4[ni] + bi4[ni];
        v = __half2float(__float2half(v));  // fc1 rounds to fp16 (reference)
        const float gl = 0.5f * v * (1.f + erff(v * 0.70710678118654752f));
        rowmax = fmaxf(rowmax, fabsf(gl));
        if (valid && cok[ni]) gout[t * (long long)N + cidx[ni]] = __float2half(gl);
      }
#pragma unroll
      for (int m = 1; m < 16; m <<= 1) rowmax = fmaxf(rowmax, __shfl_xor(rowmax, m));
      if (valid && lh == 0) atomicMax(&amax[t], __float_as_uint(rowmax));
    }
  }
}

// ---------------------------------------------------------------------------
// fc2 split-K GEMM: r15-proven 128x128 / 4-wave / 32KB dbuf frame, K split in
// 2 halves. 1D grid of 850 blocks, z = bid&1 (interleaved so both halves are
// co-resident -> ~3.3 blocks/CU demanded vs measured ~2.6 cap; the 425-block
// grid was supply-limited at 1.66/CU). Writes int32 partials (exact).
// pbuf[2][M][N] aliases gbuf (both 52.48 MB; gbuf dead after gelu_quant).
// ---------------------------------------------------------------------------
__launch_bounds__(256, 4)
__global__ void gemm_fc2s(const signed char* __restrict__ A, const signed char* __restrict__ Bw,
                          int M, int N, int K, int* __restrict__ pbuf) {
  __shared__ __align__(16) char lds[2][2][128 * 64];
  const int tid = threadIdx.x;
  const int lane = tid & 63, wave = tid >> 6;
  const int wrow = (wave >> 1) * 64, wcol = (wave & 1) * 64;

  // decompose: z interleaved, then bijective XCD swizzle over the 425 tiles
  const int z = blockIdx.x & 1;
  const int o = blockIdx.x >> 1;
  const int gy = (M + 127) >> 7;                  // 17
  const int nwg = gridDim.x >> 1;                 // 425
  int lid;
  {
    const int q = nwg >> 3, r = nwg & 7;
    const int x = o & 7, p = o >> 3;
    lid = (x < r ? x * (q + 1) : r * (q + 1) + (x - r) * q) + p;
  }
  const long long t0 = (long long)(lid % gy) * 128;
  const long long n0 = (long long)(lid / gy) * 128;
  const int koff = z * (K >> 1);
  const int nk = (K >> 1) >> 6;                   // 100
  const long long Mm1 = M - 1, Nm1 = N - 1;

  // hoisted staging pointers (2 chunks/wave A + 2 B), global-side XOR
  const signed char* sp[4];
  int dst[4];
#pragma unroll
  for (int i = 0; i < 4; ++i) {
    const bool isA = i < 2;
    const int c = wave * 2 + (i & 1);
    const int lr = c * 16 + (lane >> 2);
    const int gslot = (((lane & 3) ^ ((lr >> 1) & 3)) << 4);
    long long gr = (isA ? t0 : n0) + lr;
    const long long rmax = isA ? Mm1 : Nm1;
    if (gr > rmax) gr = rmax;
    sp[i] = (isA ? A : Bw) + gr * (long long)K + koff + gslot;
    dst[i] = (isA ? 0 : 8192) + c * 1024;
  }

#define STAGE(bi) do { \
    _Pragma("unroll") \
    for (int i = 0; i < 4; ++i) { \
      __builtin_amdgcn_global_load_lds(AS1C(sp[i]), AS3(&lds[bi][0][0] + dst[i]), 16, 0, 0); \
      sp[i] += 64; \
    } \
  } while (0)

  const int srow = lane & 15, sseg = lane >> 4;
  const int xs = ((sseg ^ ((srow >> 1) & 3)) << 4);
  const int offA = (wrow + srow) * 64 + xs;          // + mi*1024
  const int offB = 8192 + (wcol + srow) * 64 + xs;   // + ni*1024

  v4i acc[4][4] = {};

  STAGE(0);
  __syncthreads();

  int cur = 0;
  for (int kt = 0; kt < nk; ++kt) {
    if (kt + 1 < nk) STAGE(cur ^ 1);
    const char* base = &lds[cur][0][0];
    v4i af[4], bf[4];
#pragma unroll
    for (int mi = 0; mi < 4; ++mi) af[mi] = *(const v4i*)(base + offA + mi * 1024);
#pragma unroll
    for (int ni = 0; ni < 4; ++ni) bf[ni] = *(const v4i*)(base + offB + ni * 1024);
#pragma unroll
    for (int mi = 0; mi < 4; ++mi)
#pragma unroll
      for (int ni = 0; ni < 4; ++ni)
        acc[mi][ni] = __builtin_amdgcn_mfma_i32_16x16x64_i8(af[mi], bf[ni], acc[mi][ni], 0, 0, 0);
    __syncthreads();
    cur ^= 1;
  }
#undef STAGE

  // write int32 partials
  const long long zbase = (long long)z * M * N;
#pragma unroll
  for (int mi = 0; mi < 4; ++mi) {
#pragma unroll
    for (int j = 0; j < 4; ++j) {
      const long long t = t0 + wrow + mi * 16 + (lane >> 4) * 4 + j;
      if (t < M) {
#pragma unroll
        for (int ni = 0; ni < 4; ++ni) {
          const long long c = n0 + wcol + ni * 16 + (lane & 15);
          pbuf[zbase + t * (long long)N + c] = acc[mi][ni][j];
        }
      }
    }
  }
}

// ---------------------------------------------------------------------------
// fc2 reduce: out = fp16round((P0+P1) * fp16(amax/127) * wsc + bias), f32 out
// ---------------------------------------------------------------------------
__global__ void fc2_reduce(const int* __restrict__ pbuf, const unsigned int* __restrict__ amax,
                           const float* __restrict__ wsc, const float* __restrict__ bias,
                           float* __restrict__ out, int T_, int N_) {
  const long long MN = (long long)T_ * N_;
  const long long nchunk = MN >> 2;            // N % 4 == 0, no row crossing
  const long long stride = (long long)gridDim.x * blockDim.x;
  for (long long cchunk = blockIdx.x * (long long)blockDim.x + threadIdx.x;
       cchunk < nchunk; cchunk += stride) {
    const long long base = cchunk << 2;
    const int t = (int)(base / N_);
    const int n = (int)(base - (long long)t * N_);
    const float am = __uint_as_float(amax[t]);
    const float st = __half2float(__float2half(am * (1.f / 127.f)));
    const int4 p0 = *(const int4*)(pbuf + base);
    const int4 p1 = *(const int4*)(pbuf + MN + base);
    const float4 w = *(const float4*)(wsc + n);
    const float4 b = *(const float4*)(bias + n);
    float4 o;
    o.x = __half2float(__float2half((float)(p0.x + p1.x) * st * w.x + b.x));
    o.y = __half2float(__float2half((float)(p0.y + p1.y) * st * w.y + b.y));
    o.z = __half2float(__float2half((float)(p0.z + p1.z) * st * w.z + b.z));
    o.w = __half2float(__float2half((float)(p0.w + p1.w) * st * w.w + b.w));
    *(float4*)(out + base) = o;
  }
}

// ---------------------------------------------------------------------------
// per-token dynamic int8 quantization of the GELU output
// ---------------------------------------------------------------------------
__global__ void gelu_quant(const __half* __restrict__ g, const unsigned int* __restrict__ amax,
                           signed char* __restrict__ q, long long total, int I) {
  const long long nchunk = total >> 3;
  const long long stride = (long long)gridDim.x * blockDim.x;
  for (long long c = blockIdx.x * (long long)blockDim.x + threadIdx.x; c < nchunk; c += stride) {
    const long long base = c << 3;  // 8 elems, never crosses a row (I % 8 == 0)
    const int t = (int)(base / I);
    const float am = __uint_as_float(amax[t]);
    const float s = fmaxf(__half2float(__float2half(am * (1.f / 127.f))), 1e-8f);
    const float inv = 1.f / s;
    const int4 raw = *(const int4*)(g + base);
    const __half2* h2 = (const __half2*)&raw;
    union { signed char b[8]; int2 v; } u;
#pragma unroll
    for (int k = 0; k < 4; ++k) {
      const float2 f = __half22float2(h2[k]);
      const float q0 = fminf(fmaxf(rintf(f.x * inv), -128.f), 127.f);
      const float q1 = fminf(fmaxf(rintf(f.y * inv), -128.f), 127.f);
      u.b[k * 2]     = (signed char)(int)q0;
      u.b[k * 2 + 1] = (signed char)(int)q1;
    }
    *(int2*)(q + base) = u.v;
  }
}

extern "C" void kernel_launch(void* const* d_in, const int* in_sizes, int n_in,
                              void* d_out, int out_size, void* d_ws, size_t ws_size,
                              hipStream_t stream) {
  const int* hs = (const int*)d_in[0];
  const float* scale_in = (const float*)d_in[1];   // fp16 in reference -> f32 buffer
  const int* w1 = (const int*)d_in[2];
  const float* w1s = (const float*)d_in[3];
  const float* b1 = (const float*)d_in[4];
  const int* w2 = (const int*)d_in[5];
  const float* w2s = (const float*)d_in[6];
  const float* b2 = (const float*)d_in[7];

  const int T = in_sizes[1];        // 2050
  const int I = in_sizes[3];        // 12800
  const int H = in_sizes[6];        // 3200

  char* ws = (char*)d_ws;
  unsigned int* amax = (unsigned int*)ws;                    // T u32 (16KB pad)
  signed char* px  = (signed char*)(ws + 16384);             // T*H
  signed char* pw1 = px + (size_t)T * H;                     // I*H
  signed char* pw2 = pw1 + (size_t)I * H;                    // H*I
  __half* gbuf = (__half*)(pw2 + (size_t)H * I);             // T*I fp16
  signed char* qbuf = (signed char*)(gbuf + (size_t)T * I);  // T*I
  int* pbuf = (int*)gbuf;   // aliases gbuf: 2*T*H*4 = T*I*2 bytes (both 52.48MB);
                            // gbuf is dead after gelu_quant (stream-ordered)

  const long long nx = (long long)T * H, nw1 = (long long)I * H, nw2 = (long long)H * I;

  // pack x + w1 (+ amax zero) — must precede fc1
  pack1<<<2048, 256, 0, stream>>>(hs, w1, px, pw1, amax, nx, nw1, T);

  // fc1 (256x256, 16 waves) fused with w2 packing; 62 + 450 = 512 blocks
  const int NPACK = 62;
  const int gy1 = (T + 255) / 256;                 // 9
  const int gemmBlocks = (I / 256) * gy1;          // 450
  fc1_fused<<<NPACK + gemmBlocks, 1024, 0, stream>>>(
      px, pw1, T, I, H, scale_in, w1s, b1, gbuf, amax,
      w2, pw2, nw2 >> 2, NPACK, gy1);

  gelu_quant<<<2048, 256, 0, stream>>>(gbuf, amax, qbuf, (long long)T * I, I);

  // fc2 split-K: 2 x (25 x 17) = 850 blocks, interleaved halves
  const int tiles2 = (H / 128) * ((T + 127) / 128);   // 425
  gemm_fc2s<<<tiles2 * 2, 256, 0, stream>>>(qbuf, pw2, T, H, I, pbuf);

  fc2_reduce<<<2048, 256, 0, stream>>>(pbuf, amax, w2s, b2, (float*)d_out, T, H);
}